// Round 1
// baseline (345.162 us; speedup 1.0000x reference)
//
#include <hip/hip_runtime.h>
#include <hip/hip_bf16.h>

#define B_N 8192
#define C_DIM 512

typedef __attribute__((ext_vector_type(4))) float f32x4;
typedef __attribute__((ext_vector_type(8))) __bf16 bf16x8;

__device__ __forceinline__ unsigned short f2bf(float f) {
    unsigned int u = __float_as_uint(f);
    u += 0x7FFFu + ((u >> 16) & 1u);          // RNE
    return (unsigned short)(u >> 16);
}
__device__ __forceinline__ float bf2f(unsigned short s) {
    return __uint_as_float(((unsigned int)s) << 16);
}

// ---- detect whether target buffer is int64 (odd words all zero) or int32 ----
__global__ void detect_i64(const unsigned int* __restrict__ t, int* __restrict__ flag) {
    __shared__ int bad;
    if (threadIdx.x == 0) bad = 0;
    __syncthreads();
    int local = 0;
    for (int k = (int)threadIdx.x; k < 4096; k += 256)
        if (t[2 * k + 1] != 0u) local = 1;
    if (local) atomicOr(&bad, 1);
    __syncthreads();
    if (threadIdx.x == 0) *flag = (bad == 0) ? 1 : 0;   // 1 => int64 layout
}

// ---- L2 normalize rows, emit bf16 ----
__global__ __launch_bounds__(256) void normalize_k(const float* __restrict__ x,
                                                   unsigned short* __restrict__ nf) {
    const int wid = threadIdx.x >> 6, lane = threadIdx.x & 63;
    const size_t row = (size_t)blockIdx.x * 4 + wid;
    const float4* xr = (const float4*)(x + row * C_DIM) + lane * 2;
    float4 a = xr[0], b = xr[1];
    float ss = a.x * a.x + a.y * a.y + a.z * a.z + a.w * a.w +
               b.x * b.x + b.y * b.y + b.z * b.z + b.w * b.w;
#pragma unroll
    for (int m = 1; m < 64; m <<= 1) ss += __shfl_xor(ss, m);
    float sc = 1.0f / fmaxf(sqrtf(ss), 1e-12f);
    union { unsigned short s[8]; int4 v; } o;
    o.s[0] = f2bf(a.x * sc); o.s[1] = f2bf(a.y * sc);
    o.s[2] = f2bf(a.z * sc); o.s[3] = f2bf(a.w * sc);
    o.s[4] = f2bf(b.x * sc); o.s[5] = f2bf(b.y * sc);
    o.s[6] = f2bf(b.z * sc); o.s[7] = f2bf(b.w * sc);
    *(int4*)(nf + row * C_DIM + lane * 8) = o.v;
}

// ---- sim = nf @ nf^T (bf16 MFMA, 128x128 tile, BK=64), chunk rows ----
__global__ __launch_bounds__(256) void gemm_sim(const unsigned short* __restrict__ nf,
                                                unsigned short* __restrict__ sim,
                                                int rowBase) {
    __shared__ unsigned short As[128][72];   // +8 pad: conflict-free b128 r/w
    __shared__ unsigned short Bs[128][72];
    const int tid = threadIdx.x;
    const int wid = tid >> 6, lane = tid & 63;
    const int wm = wid >> 1, wn = wid & 1;
    const int gr = rowBase + blockIdx.y * 128;   // A rows (global)
    const int gc = blockIdx.x * 128;             // B rows = output cols
    f32x4 zero = {0.f, 0.f, 0.f, 0.f};
    f32x4 acc[4][4];
#pragma unroll
    for (int m = 0; m < 4; ++m)
#pragma unroll
        for (int n = 0; n < 4; ++n) acc[m][n] = zero;

    for (int k0 = 0; k0 < C_DIM; k0 += 64) {
#pragma unroll
        for (int q = 0; q < 4; ++q) {
            int idx = q * 256 + tid;             // 1024 chunks of 16B per tile
            int r = idx >> 3, c = (idx & 7) << 3;
            *(int4*)&As[r][c] = *(const int4*)(nf + (size_t)(gr + r) * C_DIM + k0 + c);
            *(int4*)&Bs[r][c] = *(const int4*)(nf + (size_t)(gc + r) * C_DIM + k0 + c);
        }
        __syncthreads();
#pragma unroll
        for (int kk = 0; kk < 2; ++kk) {
            const int krow = kk * 32 + (lane >> 4) * 8;
            bf16x8 a[4], b[4];
#pragma unroll
            for (int m = 0; m < 4; ++m)
                a[m] = *(const bf16x8*)&As[wm * 64 + m * 16 + (lane & 15)][krow];
#pragma unroll
            for (int n = 0; n < 4; ++n)
                b[n] = *(const bf16x8*)&Bs[wn * 64 + n * 16 + (lane & 15)][krow];
#pragma unroll
            for (int m = 0; m < 4; ++m)
#pragma unroll
                for (int n = 0; n < 4; ++n)
                    acc[m][n] = __builtin_amdgcn_mfma_f32_16x16x32_bf16(a[m], b[n], acc[m][n], 0, 0, 0);
        }
        __syncthreads();
    }
    // C/D layout: col = lane&15, row = (lane>>4)*4 + j   [m89-verified]
    const int lrowBase = blockIdx.y * 128 + wm * 64;
#pragma unroll
    for (int m = 0; m < 4; ++m) {
        int r0 = lrowBase + m * 16 + ((lane >> 4) << 2);
#pragma unroll
        for (int n = 0; n < 4; ++n) {
            int col = gc + wn * 64 + n * 16 + (lane & 15);
#pragma unroll
            for (int j = 0; j < 4; ++j)
                sim[(size_t)(r0 + j) * B_N + col] = f2bf(acc[m][n][j]);
        }
    }
}

// ---- per-row: bottom-8 same-class, top-64 other-class (radix select), loss ----
__global__ __launch_bounds__(256) void select_loss(const unsigned short* __restrict__ sim,
                                                   const unsigned int* __restrict__ tgt,
                                                   const int* __restrict__ flagp,
                                                   float* __restrict__ out, int rowBase) {
    __shared__ unsigned short negk[8192];   // order-preserving 16-bit keys (0 = masked)
    __shared__ unsigned char tgl[8192];
    __shared__ float posv[1024];
    __shared__ int hist[256];
    __shared__ float red[256];
    __shared__ int redi[256];
    __shared__ float pvals[8];
    __shared__ int np, s_digit, s_krem;

    const int tid = threadIdx.x;
    const int row = rowBase + blockIdx.x;
    const int flag = *flagp;
    if (tid == 0) np = 0;
    for (int j = tid; j < 8192; j += 256)
        tgl[j] = (unsigned char)(flag ? tgt[2 * j] : tgt[j]);
    __syncthreads();
    const int ti = tgl[row];
    const unsigned short* srow = sim + (size_t)blockIdx.x * B_N;

    for (int j8 = tid; j8 < 1024; j8 += 256) {
        union { int4 v; unsigned short s[8]; } u;
        u.v = *(const int4*)(srow + j8 * 8);
#pragma unroll
        for (int e = 0; e < 8; ++e) {
            int j = j8 * 8 + e;
            unsigned short ub = u.s[e];
            if (tgl[j] == ti) {
                negk[j] = 0;
                int p = atomicAdd(&np, 1);
                if (p < 1024) posv[p] = bf2f(ub);
            } else {
                negk[j] = (ub & 0x8000u) ? (unsigned short)(~ub)
                                         : (unsigned short)(ub | 0x8000u);
            }
        }
    }
    __syncthreads();
    const int n_pos = (np < 1024) ? np : 1024;

    // 8x block arg-min extraction of the smallest positives
    for (int it = 0; it < 8; ++it) {
        float lv = INFINITY; int li = -1;
        for (int j = tid; j < n_pos; j += 256) {
            float v = posv[j];
            if (v < lv) { lv = v; li = j; }
        }
        red[tid] = lv; redi[tid] = li;
        __syncthreads();
#pragma unroll
        for (int s = 128; s > 0; s >>= 1) {
            if (tid < s && red[tid + s] < red[tid]) { red[tid] = red[tid + s]; redi[tid] = redi[tid + s]; }
            __syncthreads();
        }
        if (tid == 0) { pvals[it] = red[0]; if (redi[0] >= 0) posv[redi[0]] = INFINITY; }
        __syncthreads();
    }

    // radix-select the 64th-largest key (2 byte passes)
    unsigned int prefix = 0, pmask = 0; int krem = 64;
    for (int b = 1; b >= 0; --b) {
        hist[tid] = 0;
        __syncthreads();
        for (int j = tid; j < 8192; j += 256) {
            unsigned int key = negk[j];
            if ((key & pmask) == prefix) atomicAdd(&hist[(key >> (8 * b)) & 255u], 1);
        }
        __syncthreads();
        if (tid == 0) {
            int c = 0, d = 255;
            for (; d > 0; --d) { int h = hist[d]; if (c + h >= krem) break; c += h; }
            s_digit = d; s_krem = krem - c;
        }
        __syncthreads();
        prefix |= ((unsigned)s_digit) << (8 * b);
        pmask |= 0xFFu << (8 * b);
        krem = s_krem;
        __syncthreads();
    }

    // sum exp(2v) over keys strictly above threshold; add krem ties at threshold
    float lsum = 0.f;
    for (int j = tid; j < 8192; j += 256) {
        unsigned int key = negk[j];
        if (key > prefix) {
            unsigned short ub = (key & 0x8000u) ? (unsigned short)(key ^ 0x8000u)
                                                : (unsigned short)(~key);
            lsum += __expf(2.0f * bf2f(ub));
        }
    }
    red[tid] = lsum;
    __syncthreads();
#pragma unroll
    for (int s = 128; s > 0; s >>= 1) {
        if (tid < s) red[tid] += red[tid + s];
        __syncthreads();
    }
    if (tid == 0) {
        float S = red[0];
        if (prefix != 0u) {
            unsigned short ub = (prefix & 0x8000u) ? (unsigned short)(prefix ^ 0x8000u)
                                                   : (unsigned short)(~prefix);
            S += (float)krem * __expf(2.0f * bf2f(ub));
        }
        float accum = 0.f;
#pragma unroll
        for (int it = 0; it < 8; ++it) {
            float p = pvals[it];
            if (p < INFINITY) {                        // +inf => <8 positives => 0 contribution
                float l = logf(__expf(2.0f * p) + S) - 2.0f * p;
                accum += l;
            }
        }
        out[row] = accum * 0.125f;
    }
}

extern "C" void kernel_launch(void* const* d_in, const int* in_sizes, int n_in,
                              void* d_out, int out_size, void* d_ws, size_t ws_size,
                              hipStream_t stream) {
    const float* newf = (const float*)d_in[1];
    const unsigned int* tgtw = (const unsigned int*)d_in[2];
    float* out = (float*)d_out;
    char* ws = (char*)d_ws;
    int* flag = (int*)ws;
    unsigned short* nf = (unsigned short*)(ws + 256);
    unsigned short* sim = (unsigned short*)(ws + 256 + (size_t)B_N * C_DIM * 2);

    size_t fixed = 256 + (size_t)B_N * C_DIM * 2;
    size_t avail = (ws_size > fixed) ? (ws_size - fixed) : 0;
    long maxRows = (long)(avail / ((size_t)B_N * 2));
    int chunk = (int)((maxRows / 128) * 128);
    if (chunk < 128) chunk = 128;
    if (chunk > B_N) chunk = B_N;

    hipLaunchKernelGGL(detect_i64, dim3(1), dim3(256), 0, stream, tgtw, flag);
    hipLaunchKernelGGL(normalize_k, dim3(B_N / 4), dim3(256), 0, stream, newf, nf);
    for (int r0 = 0; r0 < B_N; r0 += chunk) {
        int rows = (B_N - r0 < chunk) ? (B_N - r0) : chunk;
        hipLaunchKernelGGL(gemm_sim, dim3(64, rows / 128), dim3(256), 0, stream, nf, sim, r0);
        hipLaunchKernelGGL(select_loss, dim3(rows), dim3(256), 0, stream, sim, tgtw, flag, out, r0);
    }
}

// Round 2
// 263.863 us; speedup vs baseline: 1.3081x; 1.3081x over previous
//
#include <hip/hip_runtime.h>
#include <hip/hip_bf16.h>

#define B_N 8192
#define C_DIM 512

typedef __attribute__((ext_vector_type(4))) float f32x4;
typedef __attribute__((ext_vector_type(8))) __bf16 bf16x8;

__device__ __forceinline__ unsigned short f2bf(float f) {
    unsigned int u = __float_as_uint(f);
    u += 0x7FFFu + ((u >> 16) & 1u);          // RNE
    return (unsigned short)(u >> 16);
}
__device__ __forceinline__ float bf2f(unsigned int s) {
    return __uint_as_float(s << 16);
}
// order-preserving key: float order -> unsigned ascending. 0 reserved (real keys >= ~0x4000)
__device__ __forceinline__ unsigned negkey(unsigned ub) {
    return ub ^ ((ub & 0x8000u) ? 0xFFFFu : 0x8000u);
}
__device__ __forceinline__ float negkey2f(unsigned key) {
    unsigned ub = (key & 0x8000u) ? (key ^ 0x8000u) : ((~key) & 0xFFFFu);
    return bf2f(ub);
}
__device__ __forceinline__ float poskey2f(unsigned key) { return negkey2f(key ^ 0xFFFFu); }

// ---- detect int64-vs-int32 target layout, emit class bytes ----
__global__ void prep_tgt(const unsigned int* __restrict__ t, unsigned char* __restrict__ tgb) {
    __shared__ int bad;
    if (threadIdx.x == 0) bad = 0;
    __syncthreads();
    int local = 0;
    for (int k = (int)threadIdx.x; k < 4096; k += 256)   // reads only first 32KB: safe for both layouts
        if (t[2 * k + 1] != 0u) local = 1;
    if (local) atomicOr(&bad, 1);
    __syncthreads();
    const int is64 = (bad == 0);
    for (int j = (int)threadIdx.x; j < B_N; j += 256)
        tgb[j] = (unsigned char)(is64 ? t[2 * j] : t[j]);
}

// ---- L2 normalize rows, emit bf16 ----
__global__ __launch_bounds__(256) void normalize_k(const float* __restrict__ x,
                                                   unsigned short* __restrict__ nf) {
    const int wid = threadIdx.x >> 6, lane = threadIdx.x & 63;
    const size_t row = (size_t)blockIdx.x * 4 + wid;
    const float4* xr = (const float4*)(x + row * C_DIM) + lane * 2;
    float4 a = xr[0], b = xr[1];
    float ss = a.x * a.x + a.y * a.y + a.z * a.z + a.w * a.w +
               b.x * b.x + b.y * b.y + b.z * b.z + b.w * b.w;
#pragma unroll
    for (int m = 1; m < 64; m <<= 1) ss += __shfl_xor(ss, m);
    float sc = 1.0f / fmaxf(sqrtf(ss), 1e-12f);
    union { unsigned short s[8]; int4 v; } o;
    o.s[0] = f2bf(a.x * sc); o.s[1] = f2bf(a.y * sc);
    o.s[2] = f2bf(a.z * sc); o.s[3] = f2bf(a.w * sc);
    o.s[4] = f2bf(b.x * sc); o.s[5] = f2bf(b.y * sc);
    o.s[6] = f2bf(b.z * sc); o.s[7] = f2bf(b.w * sc);
    *(int4*)(nf + row * C_DIM + lane * 8) = o.v;
}

// ---- sim = nf @ nf^T (bf16 MFMA, 128x128 tile, BK=64), chunk rows ----
__global__ __launch_bounds__(256) void gemm_sim(const unsigned short* __restrict__ nf,
                                                unsigned short* __restrict__ sim,
                                                int rowBase) {
    __shared__ unsigned short As[128][72];
    __shared__ unsigned short Bs[128][72];
    const int tid = threadIdx.x;
    const int wid = tid >> 6, lane = tid & 63;
    const int wm = wid >> 1, wn = wid & 1;
    const int gr = rowBase + blockIdx.y * 128;
    const int gc = blockIdx.x * 128;
    f32x4 zero = {0.f, 0.f, 0.f, 0.f};
    f32x4 acc[4][4];
#pragma unroll
    for (int m = 0; m < 4; ++m)
#pragma unroll
        for (int n = 0; n < 4; ++n) acc[m][n] = zero;

    for (int k0 = 0; k0 < C_DIM; k0 += 64) {
#pragma unroll
        for (int q = 0; q < 4; ++q) {
            int idx = q * 256 + tid;
            int r = idx >> 3, c = (idx & 7) << 3;
            *(int4*)&As[r][c] = *(const int4*)(nf + (size_t)(gr + r) * C_DIM + k0 + c);
            *(int4*)&Bs[r][c] = *(const int4*)(nf + (size_t)(gc + r) * C_DIM + k0 + c);
        }
        __syncthreads();
#pragma unroll
        for (int kk = 0; kk < 2; ++kk) {
            const int krow = kk * 32 + (lane >> 4) * 8;
            bf16x8 a[4], b[4];
#pragma unroll
            for (int m = 0; m < 4; ++m)
                a[m] = *(const bf16x8*)&As[wm * 64 + m * 16 + (lane & 15)][krow];
#pragma unroll
            for (int n = 0; n < 4; ++n)
                b[n] = *(const bf16x8*)&Bs[wn * 64 + n * 16 + (lane & 15)][krow];
#pragma unroll
            for (int m = 0; m < 4; ++m)
#pragma unroll
                for (int n = 0; n < 4; ++n)
                    acc[m][n] = __builtin_amdgcn_mfma_f32_16x16x32_bf16(a[m], b[n], acc[m][n], 0, 0, 0);
        }
        __syncthreads();
    }
    const int lrowBase = blockIdx.y * 128 + wm * 64;
#pragma unroll
    for (int m = 0; m < 4; ++m) {
        int r0 = lrowBase + m * 16 + ((lane >> 4) << 2);
#pragma unroll
        for (int n = 0; n < 4; ++n) {
            int col = gc + wn * 64 + n * 16 + (lane & 15);
#pragma unroll
            for (int j = 0; j < 4; ++j)
                sim[(size_t)(r0 + j) * B_N + col] = f2bf(acc[m][n][j]);
        }
    }
}

// ---- per-row: radix-select top-64 negs & bottom-8 pos, loss. 1 row/block ----
// thread tid owns elements j = q*2048 + tid*8 + e  (q=0..3, e=0..7), in registers.
__global__ __launch_bounds__(256) void select_loss(const unsigned short* __restrict__ sim,
                                                   const unsigned char* __restrict__ tgb,
                                                   float* __restrict__ out, int rowBase) {
    __shared__ int h[4][256];
    __shared__ int s_digit, s_krem;
    __shared__ float s_partial[4];
    __shared__ float posbuf[8];
    __shared__ int posn;

    const int tid = threadIdx.x;
    const int wid = tid >> 6, lane = tid & 63;
    const int row = rowBase + blockIdx.x;
    const unsigned short* srow = sim + (size_t)blockIdx.x * B_N;
    const int ti = tgb[row];
    if (tid == 0) posn = 0;

    // load 32 sims + class mask into registers (coalesced 16B/8B per lane)
    int4 A[4];
    unsigned cmask = 0;     // bit (q*8+e) = same-class
#pragma unroll
    for (int q = 0; q < 4; ++q) {
        A[q] = *(const int4*)(srow + q * 2048 + tid * 8);
        int2 tb = *(const int2*)(tgb + q * 2048 + tid * 8);
#pragma unroll
        for (int e = 0; e < 8; ++e) {
            unsigned byte = (unsigned)((e < 4 ? (tb.x >> (8 * e)) : (tb.y >> (8 * (e - 4)))) & 255);
            if ((int)byte == ti) cmask |= 1u << (q * 8 + e);
        }
    }

    // ---------- two radix selects: side=0 -> negatives (k=64), side=1 -> positives (k=8)
    unsigned nprefix = 0, pprefix = 0;
    int nkrem = 0, pkrem = 0;
#pragma unroll
    for (int side = 0; side < 2; ++side) {
        unsigned pref = 0, pmask = 0;
        int krem = side ? 8 : 64;
#pragma unroll
        for (int bshift = 8; bshift >= 0; bshift -= 8) {
            // zero hist
#pragma unroll
            for (int w = 0; w < 4; ++w) h[w][tid] = 0;
            __syncthreads();
            // histogram this byte over the active side & prefix-match
#pragma unroll
            for (int q = 0; q < 4; ++q) {
#pragma unroll
                for (int d = 0; d < 4; ++d) {
                    unsigned w32 = (unsigned)(d == 0 ? A[q].x : d == 1 ? A[q].y : d == 2 ? A[q].z : A[q].w);
#pragma unroll
                    for (int hl = 0; hl < 2; ++hl) {
                        const int bidx = q * 8 + d * 2 + hl;
                        unsigned ub = hl ? (w32 >> 16) : (w32 & 0xFFFFu);
                        unsigned key = negkey(ub);
                        if (side) key ^= 0xFFFFu;
                        bool onside = ((cmask >> bidx) & 1u) == (unsigned)side;
                        if (onside && ((key & pmask) == pref))
                            atomicAdd(&h[wid][(key >> bshift) & 255u], 1);
                    }
                }
            }
            __syncthreads();
            // wave-0 computes threshold digit via shfl suffix-scan over 256 bins
            if (wid == 0) {
                const int d0 = lane * 4;
                int a0 = h[0][d0] + h[1][d0] + h[2][d0] + h[3][d0];
                int a1 = h[0][d0+1] + h[1][d0+1] + h[2][d0+1] + h[3][d0+1];
                int a2 = h[0][d0+2] + h[1][d0+2] + h[2][d0+2] + h[3][d0+2];
                int a3 = h[0][d0+3] + h[1][d0+3] + h[2][d0+3] + h[3][d0+3];
                int ls3 = a3, ls2 = a2 + ls3, ls1 = a1 + ls2, ls0 = a0 + ls1;
                int s = ls0;                                    // wave inclusive suffix of lane totals
#pragma unroll
                for (int off = 1; off < 64; off <<= 1) {
                    int t = __shfl_down(s, off);
                    if (lane + off < 64) s += t;
                }
                const int E = s - ls0;                          // sum over lanes > lane
                bool c3 = (E + ls3) >= krem, c2 = (E + ls2) >= krem,
                     c1 = (E + ls1) >= krem, c0 = (E + ls0) >= krem;
                int bestk = c3 ? 3 : c2 ? 2 : c1 ? 1 : c0 ? 0 : -1;
                unsigned long long m = __ballot(bestk >= 0);
                int hi = m ? (63 - __clzll(m)) : 0;
                if (lane == hi) {
                    int k = (m ? bestk : 0);
                    int ak   = (k == 0 ? a0 : k == 1 ? a1 : k == 2 ? a2 : a3);
                    int lsk  = (k == 0 ? ls0 : k == 1 ? ls1 : k == 2 ? ls2 : ls3);
                    int cInc = E + lsk;
                    s_digit = d0 + k;
                    s_krem  = krem - (cInc - ak);
                }
            }
            __syncthreads();
            pref |= ((unsigned)s_digit) << bshift;
            pmask |= 0xFFu << bshift;
            krem = s_krem;
            __syncthreads();
        }
        if (side) { pprefix = pref; pkrem = krem; }
        else      { nprefix = pref; nkrem = krem; }
    }

    // ---------- final pass over registers
    float Sl = 0.f;
#pragma unroll
    for (int q = 0; q < 4; ++q) {
#pragma unroll
        for (int d = 0; d < 4; ++d) {
            unsigned w32 = (unsigned)(d == 0 ? A[q].x : d == 1 ? A[q].y : d == 2 ? A[q].z : A[q].w);
#pragma unroll
            for (int hl = 0; hl < 2; ++hl) {
                const int bidx = q * 8 + d * 2 + hl;
                unsigned ub = hl ? (w32 >> 16) : (w32 & 0xFFFFu);
                unsigned key = negkey(ub);
                bool same = (cmask >> bidx) & 1u;
                if (!same && key > nprefix)
                    Sl += __expf(2.0f * bf2f(ub));
                if (same && (key ^ 0xFFFFu) > pprefix) {
                    int p = atomicAdd(&posn, 1);
                    if (p < 8) posbuf[p] = bf2f(ub);           // provably <=7 entries
                }
            }
        }
    }
#pragma unroll
    for (int off = 1; off < 64; off <<= 1) Sl += __shfl_xor(Sl, off);
    if (lane == 0) s_partial[wid] = Sl;
    __syncthreads();

    if (tid == 0) {
        float S = s_partial[0] + s_partial[1] + s_partial[2] + s_partial[3];
        if (nprefix != 0u) S += (float)nkrem * __expf(2.0f * negkey2f(nprefix));
        float acc = 0.f;
        int c0 = posn < 8 ? posn : 8;
        for (int i = 0; i < c0; ++i) {
            float p = posbuf[i];
            acc += logf(__expf(2.0f * p) + S) - 2.0f * p;
        }
        if (pprefix != 0u) {
            float p = poskey2f(pprefix);
            acc += (float)pkrem * (logf(__expf(2.0f * p) + S) - 2.0f * p);
        }
        out[row] = acc * 0.125f;
    }
}

extern "C" void kernel_launch(void* const* d_in, const int* in_sizes, int n_in,
                              void* d_out, int out_size, void* d_ws, size_t ws_size,
                              hipStream_t stream) {
    const float* newf = (const float*)d_in[1];
    const unsigned int* tgtw = (const unsigned int*)d_in[2];
    float* out = (float*)d_out;
    char* ws = (char*)d_ws;
    unsigned char* tgb = (unsigned char*)ws;
    unsigned short* nf = (unsigned short*)(ws + 8192);
    unsigned short* sim = (unsigned short*)(ws + 8192 + (size_t)B_N * C_DIM * 2);

    size_t fixed = 8192 + (size_t)B_N * C_DIM * 2;
    size_t avail = (ws_size > fixed) ? (ws_size - fixed) : 0;
    long maxRows = (long)(avail / ((size_t)B_N * 2));
    int chunk = (int)((maxRows / 128) * 128);
    if (chunk < 128) chunk = 128;
    if (chunk > B_N) chunk = B_N;

    hipLaunchKernelGGL(prep_tgt, dim3(1), dim3(256), 0, stream, tgtw, tgb);
    hipLaunchKernelGGL(normalize_k, dim3(B_N / 4), dim3(256), 0, stream, newf, nf);
    for (int r0 = 0; r0 < B_N; r0 += chunk) {
        int rows = (B_N - r0 < chunk) ? (B_N - r0) : chunk;
        hipLaunchKernelGGL(gemm_sim, dim3(64, rows / 128), dim3(256), 0, stream, nf, sim, r0);
        hipLaunchKernelGGL(select_loss, dim3(rows), dim3(256), 0, stream, sim, tgb, out, r0);
    }
}